// Round 12
// baseline (18.778 us; speedup 1.0000x reference)
//
#include <hip/hip_runtime.h>
#include <hip/hip_bf16.h>

// out[b,d] = ortho[d,0]*(var[o,0]^2*ns[b,0]) + ortho[d,1]*(var[o,1]^2*ns[b,1]) + mu[o,d]
//   o = idx[b].  D=128, R=2, NOBJ=9.  img unused.
// R12: chunked double-buffered pipeline — GPB=32 split into 4 chunks of 8;
// prefetch chunk c+1 (16 loads in flight) while computing+storing chunk c.
// Keeps the read stream flowing under the write stream instead of the
// all-reads-then-all-writes phase structure of R11 (which saturated at 18.75).
// Ledger: NT stores -2.5us (R6); NT input loads REJECTED (R8); 512 blocks /
// GPB=32 best (R11); occupancy/VGPR never limiting (R7/R8).

#define VAE_D 128
#define CH    8     // rows-groups per chunk
#define NCH   4     // chunks per block -> GPB = 32, 512 blocks

typedef float f32x4 __attribute__((ext_vector_type(4)));

__device__ __forceinline__ void load_chunk(const int* __restrict__ idx,
                                           const float* __restrict__ ns,
                                           int gbase, int grp,
                                           int* o, float2* n)
{
    #pragma unroll
    for (int u = 0; u < CH; ++u) {
        const int b = ((gbase + u) << 3) + grp;
        o[u] = idx[b];
    }
    #pragma unroll
    for (int u = 0; u < CH; ++u) {
        const int b = ((gbase + u) << 3) + grp;
        n[u] = *reinterpret_cast<const float2*>(ns + (size_t)b * VAE_D);
    }
}

__device__ __forceinline__ void proc_chunk(const float* __restrict__ mu,
                                           const float* __restrict__ var,
                                           float* __restrict__ out,
                                           int gbase, int grp, int d0,
                                           const float2& oc0, const float2& oc1,
                                           const float2& oc2, const float2& oc3,
                                           const int* o, const float2* n)
{
    #pragma unroll
    for (int u = 0; u < CH; ++u) {
        const int b = ((gbase + u) << 3) + grp;
        const float2 v = *reinterpret_cast<const float2*>(var + o[u] * 2);
        const float a0 = v.x * v.x * n[u].x;
        const float a1 = v.y * v.y * n[u].y;
        const float4 m = *reinterpret_cast<const float4*>(mu + (size_t)o[u] * VAE_D + d0);
        f32x4 r;
        r.x = fmaf(oc0.x, a0, fmaf(oc0.y, a1, m.x));
        r.y = fmaf(oc1.x, a0, fmaf(oc1.y, a1, m.y));
        r.z = fmaf(oc2.x, a0, fmaf(oc2.y, a1, m.z));
        r.w = fmaf(oc3.x, a0, fmaf(oc3.y, a1, m.w));
        __builtin_nontemporal_store(r,
            reinterpret_cast<f32x4*>(out + (size_t)b * VAE_D + d0));
    }
}

__global__ __launch_bounds__(256)
void vae_embed_kernel(const int* __restrict__ idx,
                      const float* __restrict__ ns,      // [B, 128]
                      const float* __restrict__ ortho,   // [128, 128] row-major
                      const float* __restrict__ mu,      // [9, 128]
                      const float* __restrict__ var,     // [9, 2]
                      float* __restrict__ out,           // [B, 128]
                      int B)
{
    const int t    = threadIdx.x;
    const int lane = t & 31;            // 32 lanes cover one row (4 floats each)
    const int grp  = t >> 5;            // 8 row-slots per block
    const int d0   = lane << 2;

    // Loop-invariant ortho column pairs (L1-hot after first block per CU).
    const float2 oc0 = *reinterpret_cast<const float2*>(ortho + (size_t)(d0 + 0) * VAE_D);
    const float2 oc1 = *reinterpret_cast<const float2*>(ortho + (size_t)(d0 + 1) * VAE_D);
    const float2 oc2 = *reinterpret_cast<const float2*>(ortho + (size_t)(d0 + 2) * VAE_D);
    const float2 oc3 = *reinterpret_cast<const float2*>(ortho + (size_t)(d0 + 3) * VAE_D);

    const int groups = B >> 3;                 // row-groups of 8
    const int g0 = blockIdx.x * (CH * NCH);

    if (g0 + CH * NCH <= groups) {
        // ---- fast path: 4-stage chunked pipeline, 1-ahead prefetch ----
        int    oA[CH], oB[CH];
        float2 nA[CH], nB[CH];

        load_chunk(idx, ns, g0 + 0 * CH, grp, oA, nA);          // fill stage

        load_chunk(idx, ns, g0 + 1 * CH, grp, oB, nB);          // c=0: prefetch c=1
        proc_chunk(mu, var, out, g0 + 0 * CH, grp, d0, oc0, oc1, oc2, oc3, oA, nA);

        load_chunk(idx, ns, g0 + 2 * CH, grp, oA, nA);          // c=1: prefetch c=2
        proc_chunk(mu, var, out, g0 + 1 * CH, grp, d0, oc0, oc1, oc2, oc3, oB, nB);

        load_chunk(idx, ns, g0 + 3 * CH, grp, oB, nB);          // c=2: prefetch c=3
        proc_chunk(mu, var, out, g0 + 2 * CH, grp, d0, oc0, oc1, oc2, oc3, oA, nA);

        proc_chunk(mu, var, out, g0 + 3 * CH, grp, d0, oc0, oc1, oc2, oc3, oB, nB);  // drain
    } else {
        // ---- generic tail (unused when B % (8*CH*NCH) == 0) ----
        for (int g = g0; g < groups; ++g) {
            const int b = (g << 3) + grp;
            const int o = idx[b];
            const float2 n01 = *reinterpret_cast<const float2*>(ns + (size_t)b * VAE_D);
            const float2 v   = *reinterpret_cast<const float2*>(var + o * 2);
            const float a0 = v.x * v.x * n01.x;
            const float a1 = v.y * v.y * n01.y;
            const float4 m = *reinterpret_cast<const float4*>(mu + (size_t)o * VAE_D + d0);
            float4 r;
            r.x = fmaf(oc0.x, a0, fmaf(oc0.y, a1, m.x));
            r.y = fmaf(oc1.x, a0, fmaf(oc1.y, a1, m.y));
            r.z = fmaf(oc2.x, a0, fmaf(oc2.y, a1, m.z));
            r.w = fmaf(oc3.x, a0, fmaf(oc3.y, a1, m.w));
            *reinterpret_cast<float4*>(out + (size_t)b * VAE_D + d0) = r;
        }
    }
}

extern "C" void kernel_launch(void* const* d_in, const int* in_sizes, int n_in,
                              void* d_out, int out_size, void* d_ws, size_t ws_size,
                              hipStream_t stream)
{
    // inputs: img[B,4], random_int[B], normal_sample[B,128],
    //         orthogonal_set[128,128], mu_[9,128], var_[9,2]
    const int*   idx   = (const int*)  d_in[1];
    const float* ns    = (const float*)d_in[2];
    const float* ortho = (const float*)d_in[3];
    const float* mu    = (const float*)d_in[4];
    const float* var   = (const float*)d_in[5];
    float* out = (float*)d_out;

    const int B = in_sizes[1];
    const int groups = B >> 3;                         // 16384 for B=131072
    const int grid = (groups + CH * NCH - 1) / (CH * NCH);   // 512 blocks

    vae_embed_kernel<<<grid, 256, 0, stream>>>(idx, ns, ortho, mu, var, out, B);
}